// Round 3
// baseline (5689.193 us; speedup 1.0000x reference)
//
#include <hip/hip_runtime.h>

#define TT 10
#define NN 10000
#define CC 4
#define HH 128
#define EE 160000

typedef unsigned char u8;

// ---------------- U/V precompute: U[m=k*2+half][n][:] = h[n] @ W1[k][half*128:+128][:]
// fc1w layout (3,256,128): W1[k][f][h]; (k*256+half*128)*128 == m*16384.
__global__ __launch_bounds__(256)
void uv_kernel(const float* __restrict__ hid, const float* __restrict__ fc1w,
               float* __restrict__ UV){
  __shared__ float hL[32][136];
  const int tid = threadIdx.x;
  const int n0 = blockIdx.x << 5;
  const int m = blockIdx.y;
  const float* __restrict__ W = fc1w + (size_t)m * (HH*HH);

  #pragma unroll
  for (int it = 0; it < 4; ++it){
    int s = tid + (it << 8);          // 0..1023 float4 slots
    int r = s >> 5, c4 = s & 31;
    int node = n0 + r; if (node > NN-1) node = NN-1;
    float4 v = *(const float4*)(hid + (size_t)node*HH + (c4 << 2));
    *(float4*)(&hL[r][c4 << 2]) = v;
  }
  __syncthreads();

  const int rg = tid >> 5, cg = tid & 31;
  float acc[4][4] = {};
  for (int kk = 0; kk < HH; ++kk){
    float hv[4];
    #pragma unroll
    for (int rr = 0; rr < 4; ++rr) hv[rr] = hL[(rg << 2) + rr][kk];
    float4 wv = *(const float4*)(W + kk*HH + (cg << 2));
    #pragma unroll
    for (int rr = 0; rr < 4; ++rr){
      acc[rr][0] = fmaf(hv[rr], wv.x, acc[rr][0]);
      acc[rr][1] = fmaf(hv[rr], wv.y, acc[rr][1]);
      acc[rr][2] = fmaf(hv[rr], wv.z, acc[rr][2]);
      acc[rr][3] = fmaf(hv[rr], wv.w, acc[rr][3]);
    }
  }
  #pragma unroll
  for (int rr = 0; rr < 4; ++rr){
    int node = n0 + (rg << 2) + rr;
    if (node < NN){
      float4 o = { acc[rr][0], acc[rr][1], acc[rr][2], acc[rr][3] };
      *(float4*)(UV + ((size_t)m*NN + node)*HH + (cg << 2)) = o;
    }
  }
}

// ---------------- Edge kernel: m1 = tanh(U[k][row] + V[k][col] + b1); msg = sum_k tanh(m1@W2[k] + b2); scatter.
__global__ __launch_bounds__(256)
void edge_kernel(const int* __restrict__ edge, const float* __restrict__ UV,
                 const float* __restrict__ b1, const float* __restrict__ b2,
                 const float* __restrict__ fc2w, float* __restrict__ agg){
  __shared__ float m1L[3][32][136];
  __shared__ int er[32], ec[32];
  const int tid = threadIdx.x;
  const int e0 = blockIdx.x << 5;

  if (tid < 32) er[tid] = edge[e0 + tid];
  else if (tid < 64) ec[tid - 32] = edge[EE + e0 + tid - 32];
  __syncthreads();

  #pragma unroll
  for (int it = 0; it < 12; ++it){
    int s = tid + (it << 8);          // 0..3071 float4 slots (3*32*32)
    int k = s >> 10;
    int e = (s >> 5) & 31, c4 = s & 31;
    float4 u = *(const float4*)(UV + ((size_t)(2*k)*NN   + er[e])*HH + (c4 << 2));
    float4 v = *(const float4*)(UV + ((size_t)(2*k+1)*NN + ec[e])*HH + (c4 << 2));
    float4 b = *(const float4*)(b1 + k*HH + (c4 << 2));
    float4 o;
    o.x = tanhf(u.x + v.x + b.x);
    o.y = tanhf(u.y + v.y + b.y);
    o.z = tanhf(u.z + v.z + b.z);
    o.w = tanhf(u.w + v.w + b.w);
    *(float4*)(&m1L[k][e][c4 << 2]) = o;
  }
  __syncthreads();

  const int eg = tid >> 5, cg = tid & 31;
  float acc[4][4] = {};
  for (int k = 0; k < 3; ++k){
    const float* __restrict__ W2 = fc2w + (size_t)k*HH*HH;
    float lacc[4][4] = {};
    for (int kk = 0; kk < HH; ++kk){
      float mv[4];
      #pragma unroll
      for (int ee = 0; ee < 4; ++ee) mv[ee] = m1L[k][(eg << 2) + ee][kk];
      float4 wv = *(const float4*)(W2 + kk*HH + (cg << 2));
      #pragma unroll
      for (int ee = 0; ee < 4; ++ee){
        lacc[ee][0] = fmaf(mv[ee], wv.x, lacc[ee][0]);
        lacc[ee][1] = fmaf(mv[ee], wv.y, lacc[ee][1]);
        lacc[ee][2] = fmaf(mv[ee], wv.z, lacc[ee][2]);
        lacc[ee][3] = fmaf(mv[ee], wv.w, lacc[ee][3]);
      }
    }
    float4 bb = *(const float4*)(b2 + k*HH + (cg << 2));
    #pragma unroll
    for (int ee = 0; ee < 4; ++ee){
      acc[ee][0] += tanhf(lacc[ee][0] + bb.x);
      acc[ee][1] += tanhf(lacc[ee][1] + bb.y);
      acc[ee][2] += tanhf(lacc[ee][2] + bb.z);
      acc[ee][3] += tanhf(lacc[ee][3] + bb.w);
    }
  }
  #pragma unroll
  for (int ee = 0; ee < 4; ++ee){
    int node = ec[(eg << 2) + ee];
    float* ap = agg + (size_t)node*HH + (cg << 2);
    #pragma unroll
    for (int cc = 0; cc < 4; ++cc) atomicAdd(ap + cc, acc[ee][cc]);
  }
}

// ---------------- Node kernel: GRU gates + 3-layer output MLP + prediction.
__global__ __launch_bounds__(256)
void node_kernel(const float* __restrict__ xin, const float* __restrict__ prevpred,
                 const int* __restrict__ burn, int t,
                 const float* __restrict__ agg, float* __restrict__ hid,
                 const float* __restrict__ whr, const float* __restrict__ whi, const float* __restrict__ whh,
                 const float* __restrict__ irw, const float* __restrict__ irb,
                 const float* __restrict__ iiw, const float* __restrict__ iib,
                 const float* __restrict__ inw, const float* __restrict__ inb,
                 const float* __restrict__ o1w, const float* __restrict__ o1b,
                 const float* __restrict__ o2w, const float* __restrict__ o2b,
                 const float* __restrict__ o3w, const float* __restrict__ o3b,
                 float* __restrict__ out){
  __shared__ float aggL[32][136];
  __shared__ float hNL[32][136];
  __shared__ float p1L[32][136];
  __shared__ float p2L[32][136];
  __shared__ float xLs[32][4];
  const int tid = threadIdx.x;
  const int n0 = blockIdx.x << 5;
  const float* __restrict__ xs = (t == 0 || t < burn[0]) ? xin : prevpred;

  #pragma unroll
  for (int it = 0; it < 4; ++it){
    int s = tid + (it << 8);
    int r = s >> 5, c4 = s & 31;
    int node = n0 + r; if (node > NN-1) node = NN-1;
    float4 v = *(const float4*)(agg + (size_t)node*HH + (c4 << 2));
    *(float4*)(&aggL[r][c4 << 2]) = v;
  }
  if (tid < 128){
    int r = tid >> 2, c = tid & 3;
    int node = n0 + r; if (node > NN-1) node = NN-1;
    xLs[r][c] = xs[(size_t)node*CC + c];
  }
  __syncthreads();

  const int ng = tid >> 5, cg = tid & 31;
  // GRU matmuls: ar/ai/ah = agg @ {whr, whi, whh}
  float ar[4][4] = {}, ai[4][4] = {}, ah[4][4] = {};
  for (int kk = 0; kk < HH; ++kk){
    float av[4];
    #pragma unroll
    for (int rr = 0; rr < 4; ++rr) av[rr] = aggL[(ng << 2) + rr][kk];
    float4 wR = *(const float4*)(whr + kk*HH + (cg << 2));
    float4 wI = *(const float4*)(whi + kk*HH + (cg << 2));
    float4 wH = *(const float4*)(whh + kk*HH + (cg << 2));
    #pragma unroll
    for (int rr = 0; rr < 4; ++rr){
      ar[rr][0] = fmaf(av[rr], wR.x, ar[rr][0]); ar[rr][1] = fmaf(av[rr], wR.y, ar[rr][1]);
      ar[rr][2] = fmaf(av[rr], wR.z, ar[rr][2]); ar[rr][3] = fmaf(av[rr], wR.w, ar[rr][3]);
      ai[rr][0] = fmaf(av[rr], wI.x, ai[rr][0]); ai[rr][1] = fmaf(av[rr], wI.y, ai[rr][1]);
      ai[rr][2] = fmaf(av[rr], wI.z, ai[rr][2]); ai[rr][3] = fmaf(av[rr], wI.w, ai[rr][3]);
      ah[rr][0] = fmaf(av[rr], wH.x, ah[rr][0]); ah[rr][1] = fmaf(av[rr], wH.y, ah[rr][1]);
      ah[rr][2] = fmaf(av[rr], wH.z, ah[rr][2]); ah[rr][3] = fmaf(av[rr], wH.w, ah[rr][3]);
    }
  }
  // gates + hidden update
  {
    float4 wr4[CC], wi4[CC], wn4[CC];
    #pragma unroll
    for (int c = 0; c < CC; ++c){
      wr4[c] = *(const float4*)(irw + c*HH + (cg << 2));
      wi4[c] = *(const float4*)(iiw + c*HH + (cg << 2));
      wn4[c] = *(const float4*)(inw + c*HH + (cg << 2));
    }
    float4 rb = *(const float4*)(irb + (cg << 2));
    float4 ib = *(const float4*)(iib + (cg << 2));
    float4 nb = *(const float4*)(inb + (cg << 2));
    #pragma unroll
    for (int rr = 0; rr < 4; ++rr){
      int row = (ng << 2) + rr;
      int node = n0 + row;
      int nodec = node > NN-1 ? NN-1 : node;
      float xv[CC];
      #pragma unroll
      for (int c = 0; c < CC; ++c) xv[c] = xLs[row][c];
      #pragma unroll
      for (int cc = 0; cc < 4; ++cc){
        int col = (cg << 2) + cc;
        float xr = ((const float*)&rb)[cc], xi = ((const float*)&ib)[cc], xn = ((const float*)&nb)[cc];
        #pragma unroll
        for (int c = 0; c < CC; ++c){
          xr = fmaf(xv[c], ((const float*)&wr4[c])[cc], xr);
          xi = fmaf(xv[c], ((const float*)&wi4[c])[cc], xi);
          xn = fmaf(xv[c], ((const float*)&wn4[c])[cc], xn);
        }
        float r = 1.f / (1.f + expf(-(xr + ar[rr][cc])));
        float i = 1.f / (1.f + expf(-(xi + ai[rr][cc])));
        float n = tanhf(xn + r * ah[rr][cc]);
        float hold = hid[(size_t)nodec*HH + col];
        float hnew = (1.f - i)*n + i*hold;
        if (node < NN) hid[(size_t)node*HH + col] = hnew;
        hNL[row][col] = hnew;
      }
    }
  }
  __syncthreads();

  // out1
  {
    float q[4][4] = {};
    for (int kk = 0; kk < HH; ++kk){
      float hv[4];
      #pragma unroll
      for (int rr = 0; rr < 4; ++rr) hv[rr] = hNL[(ng << 2) + rr][kk];
      float4 wv = *(const float4*)(o1w + kk*HH + (cg << 2));
      #pragma unroll
      for (int rr = 0; rr < 4; ++rr){
        q[rr][0] = fmaf(hv[rr], wv.x, q[rr][0]); q[rr][1] = fmaf(hv[rr], wv.y, q[rr][1]);
        q[rr][2] = fmaf(hv[rr], wv.z, q[rr][2]); q[rr][3] = fmaf(hv[rr], wv.w, q[rr][3]);
      }
    }
    float4 bb = *(const float4*)(o1b + (cg << 2));
    #pragma unroll
    for (int rr = 0; rr < 4; ++rr){
      p1L[(ng << 2) + rr][(cg << 2) + 0] = fmaxf(q[rr][0] + bb.x, 0.f);
      p1L[(ng << 2) + rr][(cg << 2) + 1] = fmaxf(q[rr][1] + bb.y, 0.f);
      p1L[(ng << 2) + rr][(cg << 2) + 2] = fmaxf(q[rr][2] + bb.z, 0.f);
      p1L[(ng << 2) + rr][(cg << 2) + 3] = fmaxf(q[rr][3] + bb.w, 0.f);
    }
  }
  __syncthreads();

  // out2
  {
    float q[4][4] = {};
    for (int kk = 0; kk < HH; ++kk){
      float hv[4];
      #pragma unroll
      for (int rr = 0; rr < 4; ++rr) hv[rr] = p1L[(ng << 2) + rr][kk];
      float4 wv = *(const float4*)(o2w + kk*HH + (cg << 2));
      #pragma unroll
      for (int rr = 0; rr < 4; ++rr){
        q[rr][0] = fmaf(hv[rr], wv.x, q[rr][0]); q[rr][1] = fmaf(hv[rr], wv.y, q[rr][1]);
        q[rr][2] = fmaf(hv[rr], wv.z, q[rr][2]); q[rr][3] = fmaf(hv[rr], wv.w, q[rr][3]);
      }
    }
    float4 bb = *(const float4*)(o2b + (cg << 2));
    #pragma unroll
    for (int rr = 0; rr < 4; ++rr){
      p2L[(ng << 2) + rr][(cg << 2) + 0] = fmaxf(q[rr][0] + bb.x, 0.f);
      p2L[(ng << 2) + rr][(cg << 2) + 1] = fmaxf(q[rr][1] + bb.y, 0.f);
      p2L[(ng << 2) + rr][(cg << 2) + 2] = fmaxf(q[rr][2] + bb.z, 0.f);
      p2L[(ng << 2) + rr][(cg << 2) + 3] = fmaxf(q[rr][3] + bb.w, 0.f);
    }
  }
  __syncthreads();

  // out3: H -> 4, then pred = x + relu(...)
  if (tid < 128){
    int r = tid >> 2, c = tid & 3;
    int node = n0 + r;
    if (node < NN){
      float s = o3b[c];
      for (int kk = 0; kk < HH; ++kk) s = fmaf(p2L[r][kk], o3w[kk*CC + c], s);
      float v = fmaxf(s, 0.f);
      out[((size_t)t*NN + node)*CC + c] = xLs[r][c] + v;
    }
  }
}

extern "C" void kernel_launch(void* const* d_in, const int* in_sizes, int n_in,
                              void* d_out, int out_size, void* d_ws, size_t ws_size,
                              hipStream_t stream){
  const float* inputs = (const float*)d_in[0];
  const float* fc1w = (const float*)d_in[1];
  const float* fc1b = (const float*)d_in[2];
  const float* fc2w = (const float*)d_in[3];
  const float* fc2b = (const float*)d_in[4];
  const float* whr  = (const float*)d_in[5];
  const float* whi  = (const float*)d_in[6];
  const float* whh  = (const float*)d_in[7];
  const float* irw  = (const float*)d_in[8];
  const float* irb  = (const float*)d_in[9];
  const float* iiw  = (const float*)d_in[10];
  const float* iib  = (const float*)d_in[11];
  const float* inw  = (const float*)d_in[12];
  const float* inb  = (const float*)d_in[13];
  const float* o1w  = (const float*)d_in[14];
  const float* o1b  = (const float*)d_in[15];
  const float* o2w  = (const float*)d_in[16];
  const float* o2b  = (const float*)d_in[17];
  const float* o3w  = (const float*)d_in[18];
  const float* o3b  = (const float*)d_in[19];
  const int* edge   = (const int*)d_in[20];
  const int* burn   = (const int*)d_in[21];
  float* out = (float*)d_out;

  u8* ws = (u8*)d_ws;
  float* hid = (float*)(ws);               // N*H fp32 = 5,120,000 B
  float* agg = (float*)(ws + 5120000);     // N*H fp32 = 5,120,000 B
  float* UV  = (float*)(ws + 10240000);    // 6*N*H fp32 = 30,720,000 B

  hipMemsetAsync(hid, 0, 5120000, stream);

  const int nblk = (NN + 31) / 32;  // 313
  for (int t = 0; t < TT; ++t){
    hipMemsetAsync(agg, 0, 5120000, stream);
    hipLaunchKernelGGL(uv_kernel, dim3(nblk, 6), dim3(256), 0, stream, hid, fc1w, UV);
    hipLaunchKernelGGL(edge_kernel, dim3(EE/32), dim3(256), 0, stream,
                       edge, UV, fc1b, fc2b, fc2w, agg);
    hipLaunchKernelGGL(node_kernel, dim3(nblk), dim3(256), 0, stream,
                       inputs + (size_t)t*NN*CC, out + (size_t)(t > 0 ? t-1 : 0)*NN*CC, burn, t,
                       agg, hid, whr, whi, whh, irw, irb, iiw, iib, inw, inb,
                       o1w, o1b, o2w, o2b, o3w, o3b, out);
  }
}

// Round 5
// 5056.981 us; speedup vs baseline: 1.1250x; 1.1250x over previous
//
#include <hip/hip_runtime.h>

#define TT 10
#define NN 10000
#define CC 4
#define HH 128
#define EE 160000

typedef unsigned char u8;

// ---------------- U/V precompute: U[m=k*2+half][n][:] = h[n] @ W1[k][half*128:+128][:]
// fc1w layout (3,256,128): W1[k][f][h]; (k*256+half*128)*128 == m*16384.
__global__ __launch_bounds__(256)
void uv_kernel(const float* __restrict__ hid, const float* __restrict__ fc1w,
               float* __restrict__ UV){
  __shared__ float hL[32][136];
  const int tid = threadIdx.x;
  const int n0 = blockIdx.x << 5;
  const int m = blockIdx.y;
  const float* __restrict__ W = fc1w + (size_t)m * (HH*HH);

  #pragma unroll
  for (int it = 0; it < 4; ++it){
    int s = tid + (it << 8);          // 0..1023 float4 slots
    int r = s >> 5, c4 = s & 31;
    int node = n0 + r; if (node > NN-1) node = NN-1;
    float4 v = *(const float4*)(hid + (size_t)node*HH + (c4 << 2));
    *(float4*)(&hL[r][c4 << 2]) = v;
  }
  __syncthreads();

  const int rg = tid >> 5, cg = tid & 31;
  float acc[4][4] = {};
  for (int kk = 0; kk < HH; ++kk){
    float hv[4];
    #pragma unroll
    for (int rr = 0; rr < 4; ++rr) hv[rr] = hL[(rg << 2) + rr][kk];
    float4 wv = *(const float4*)(W + kk*HH + (cg << 2));
    #pragma unroll
    for (int rr = 0; rr < 4; ++rr){
      acc[rr][0] = fmaf(hv[rr], wv.x, acc[rr][0]);
      acc[rr][1] = fmaf(hv[rr], wv.y, acc[rr][1]);
      acc[rr][2] = fmaf(hv[rr], wv.z, acc[rr][2]);
      acc[rr][3] = fmaf(hv[rr], wv.w, acc[rr][3]);
    }
  }
  #pragma unroll
  for (int rr = 0; rr < 4; ++rr){
    int node = n0 + (rg << 2) + rr;
    if (node < NN){
      float4 o = { acc[rr][0], acc[rr][1], acc[rr][2], acc[rr][3] };
      *(float4*)(UV + ((size_t)m*NN + node)*HH + (cg << 2)) = o;
    }
  }
}

// ---------------- Edge kernel: m1 = tanh(U[k][row] + V[k][col] + b1); msg = sum_k tanh(m1@W2[k] + b2); scatter.
// One branch at a time through a single 17KB LDS buffer -> 8 blocks/CU occupancy.
__global__ __launch_bounds__(256)
void edge_kernel(const int* __restrict__ edge, const float* __restrict__ UV,
                 const float* __restrict__ b1, const float* __restrict__ b2,
                 const float* __restrict__ fc2w, float* __restrict__ agg){
  __shared__ float m1L[32][132];   // one branch: 32 edges x 128 (pad 4)
  __shared__ int er[32], ec[32];
  const int tid = threadIdx.x;
  const int e0 = blockIdx.x << 5;

  if (tid < 32) er[tid] = edge[e0 + tid];
  else if (tid < 64) ec[tid - 32] = edge[EE + e0 + tid - 32];

  const int eg = tid >> 5, cg = tid & 31;
  float acc[4][4] = {};

  for (int k = 0; k < 3; ++k){
    __syncthreads();               // indices ready (k=0) / previous matmul done
    // stage m1 for branch k: 1024 float4 slots
    #pragma unroll
    for (int it = 0; it < 4; ++it){
      int s = tid + (it << 8);
      int e = s >> 5, c4 = s & 31;
      float4 u = *(const float4*)(UV + ((size_t)(2*k)*NN   + er[e])*HH + (c4 << 2));
      float4 v = *(const float4*)(UV + ((size_t)(2*k+1)*NN + ec[e])*HH + (c4 << 2));
      float4 b = *(const float4*)(b1 + k*HH + (c4 << 2));
      float4 o;
      o.x = tanhf(u.x + v.x + b.x);
      o.y = tanhf(u.y + v.y + b.y);
      o.z = tanhf(u.z + v.z + b.z);
      o.w = tanhf(u.w + v.w + b.w);
      *(float4*)(&m1L[e][c4 << 2]) = o;
    }
    __syncthreads();

    const float* __restrict__ W2 = fc2w + (size_t)k*HH*HH;
    float lacc[4][4] = {};
    for (int kk = 0; kk < HH; kk += 4){
      float4 wv[4];
      #pragma unroll
      for (int j = 0; j < 4; ++j)
        wv[j] = *(const float4*)(W2 + (kk + j)*HH + (cg << 2));
      float4 mv[4];
      #pragma unroll
      for (int ee = 0; ee < 4; ++ee)
        mv[ee] = *(const float4*)(&m1L[(eg << 2) + ee][kk]);
      #pragma unroll
      for (int ee = 0; ee < 4; ++ee){
        const float* m = (const float*)&mv[ee];
        #pragma unroll
        for (int j = 0; j < 4; ++j){
          lacc[ee][0] = fmaf(m[j], wv[j].x, lacc[ee][0]);
          lacc[ee][1] = fmaf(m[j], wv[j].y, lacc[ee][1]);
          lacc[ee][2] = fmaf(m[j], wv[j].z, lacc[ee][2]);
          lacc[ee][3] = fmaf(m[j], wv[j].w, lacc[ee][3]);
        }
      }
    }
    float4 bb = *(const float4*)(b2 + k*HH + (cg << 2));
    #pragma unroll
    for (int ee = 0; ee < 4; ++ee){
      acc[ee][0] += tanhf(lacc[ee][0] + bb.x);
      acc[ee][1] += tanhf(lacc[ee][1] + bb.y);
      acc[ee][2] += tanhf(lacc[ee][2] + bb.z);
      acc[ee][3] += tanhf(lacc[ee][3] + bb.w);
    }
  }

  #pragma unroll
  for (int ee = 0; ee < 4; ++ee){
    int node = ec[(eg << 2) + ee];
    float* ap = agg + (size_t)node*HH + (cg << 2);
    #pragma unroll
    for (int cc = 0; cc < 4; ++cc) atomicAdd(ap + cc, acc[ee][cc]);
  }
}

// ---------------- Node kernel: GRU gates + 3-layer output MLP + prediction.
__global__ __launch_bounds__(256)
void node_kernel(const float* __restrict__ xin, const float* __restrict__ prevpred,
                 const int* __restrict__ burn, int t,
                 const float* __restrict__ agg, float* __restrict__ hid,
                 const float* __restrict__ whr, const float* __restrict__ whi, const float* __restrict__ whh,
                 const float* __restrict__ irw, const float* __restrict__ irb,
                 const float* __restrict__ iiw, const float* __restrict__ iib,
                 const float* __restrict__ inw, const float* __restrict__ inb,
                 const float* __restrict__ o1w, const float* __restrict__ o1b,
                 const float* __restrict__ o2w, const float* __restrict__ o2b,
                 const float* __restrict__ o3w, const float* __restrict__ o3b,
                 float* __restrict__ out){
  __shared__ float aggL[32][136];
  __shared__ float hNL[32][136];
  __shared__ float p1L[32][136];
  __shared__ float p2L[32][136];
  __shared__ float xLs[32][4];
  const int tid = threadIdx.x;
  const int n0 = blockIdx.x << 5;
  const float* __restrict__ xs = (t == 0 || t < burn[0]) ? xin : prevpred;

  #pragma unroll
  for (int it = 0; it < 4; ++it){
    int s = tid + (it << 8);
    int r = s >> 5, c4 = s & 31;
    int node = n0 + r; if (node > NN-1) node = NN-1;
    float4 v = *(const float4*)(agg + (size_t)node*HH + (c4 << 2));
    *(float4*)(&aggL[r][c4 << 2]) = v;
  }
  if (tid < 128){
    int r = tid >> 2, c = tid & 3;
    int node = n0 + r; if (node > NN-1) node = NN-1;
    xLs[r][c] = xs[(size_t)node*CC + c];
  }
  __syncthreads();

  const int ng = tid >> 5, cg = tid & 31;
  // GRU matmuls: ar/ai/ah = agg @ {whr, whi, whh}
  float ar[4][4] = {}, ai[4][4] = {}, ah[4][4] = {};
  for (int kk = 0; kk < HH; ++kk){
    float av[4];
    #pragma unroll
    for (int rr = 0; rr < 4; ++rr) av[rr] = aggL[(ng << 2) + rr][kk];
    float4 wR = *(const float4*)(whr + kk*HH + (cg << 2));
    float4 wI = *(const float4*)(whi + kk*HH + (cg << 2));
    float4 wH = *(const float4*)(whh + kk*HH + (cg << 2));
    #pragma unroll
    for (int rr = 0; rr < 4; ++rr){
      ar[rr][0] = fmaf(av[rr], wR.x, ar[rr][0]); ar[rr][1] = fmaf(av[rr], wR.y, ar[rr][1]);
      ar[rr][2] = fmaf(av[rr], wR.z, ar[rr][2]); ar[rr][3] = fmaf(av[rr], wR.w, ar[rr][3]);
      ai[rr][0] = fmaf(av[rr], wI.x, ai[rr][0]); ai[rr][1] = fmaf(av[rr], wI.y, ai[rr][1]);
      ai[rr][2] = fmaf(av[rr], wI.z, ai[rr][2]); ai[rr][3] = fmaf(av[rr], wI.w, ai[rr][3]);
      ah[rr][0] = fmaf(av[rr], wH.x, ah[rr][0]); ah[rr][1] = fmaf(av[rr], wH.y, ah[rr][1]);
      ah[rr][2] = fmaf(av[rr], wH.z, ah[rr][2]); ah[rr][3] = fmaf(av[rr], wH.w, ah[rr][3]);
    }
  }
  // gates + hidden update
  {
    float4 wr4[CC], wi4[CC], wn4[CC];
    #pragma unroll
    for (int c = 0; c < CC; ++c){
      wr4[c] = *(const float4*)(irw + c*HH + (cg << 2));
      wi4[c] = *(const float4*)(iiw + c*HH + (cg << 2));
      wn4[c] = *(const float4*)(inw + c*HH + (cg << 2));
    }
    float4 rb = *(const float4*)(irb + (cg << 2));
    float4 ib = *(const float4*)(iib + (cg << 2));
    float4 nb = *(const float4*)(inb + (cg << 2));
    #pragma unroll
    for (int rr = 0; rr < 4; ++rr){
      int row = (ng << 2) + rr;
      int node = n0 + row;
      int nodec = node > NN-1 ? NN-1 : node;
      float xv[CC];
      #pragma unroll
      for (int c = 0; c < CC; ++c) xv[c] = xLs[row][c];
      #pragma unroll
      for (int cc = 0; cc < 4; ++cc){
        int col = (cg << 2) + cc;
        float xr = ((const float*)&rb)[cc], xi = ((const float*)&ib)[cc], xn = ((const float*)&nb)[cc];
        #pragma unroll
        for (int c = 0; c < CC; ++c){
          xr = fmaf(xv[c], ((const float*)&wr4[c])[cc], xr);
          xi = fmaf(xv[c], ((const float*)&wi4[c])[cc], xi);
          xn = fmaf(xv[c], ((const float*)&wn4[c])[cc], xn);
        }
        float r = 1.f / (1.f + expf(-(xr + ar[rr][cc])));
        float i = 1.f / (1.f + expf(-(xi + ai[rr][cc])));
        float n = tanhf(xn + r * ah[rr][cc]);
        float hold = hid[(size_t)nodec*HH + col];
        float hnew = (1.f - i)*n + i*hold;
        if (node < NN) hid[(size_t)node*HH + col] = hnew;
        hNL[row][col] = hnew;
      }
    }
  }
  __syncthreads();

  // out1
  {
    float q[4][4] = {};
    for (int kk = 0; kk < HH; ++kk){
      float hv[4];
      #pragma unroll
      for (int rr = 0; rr < 4; ++rr) hv[rr] = hNL[(ng << 2) + rr][kk];
      float4 wv = *(const float4*)(o1w + kk*HH + (cg << 2));
      #pragma unroll
      for (int rr = 0; rr < 4; ++rr){
        q[rr][0] = fmaf(hv[rr], wv.x, q[rr][0]); q[rr][1] = fmaf(hv[rr], wv.y, q[rr][1]);
        q[rr][2] = fmaf(hv[rr], wv.z, q[rr][2]); q[rr][3] = fmaf(hv[rr], wv.w, q[rr][3]);
      }
    }
    float4 bb = *(const float4*)(o1b + (cg << 2));
    #pragma unroll
    for (int rr = 0; rr < 4; ++rr){
      p1L[(ng << 2) + rr][(cg << 2) + 0] = fmaxf(q[rr][0] + bb.x, 0.f);
      p1L[(ng << 2) + rr][(cg << 2) + 1] = fmaxf(q[rr][1] + bb.y, 0.f);
      p1L[(ng << 2) + rr][(cg << 2) + 2] = fmaxf(q[rr][2] + bb.z, 0.f);
      p1L[(ng << 2) + rr][(cg << 2) + 3] = fmaxf(q[rr][3] + bb.w, 0.f);
    }
  }
  __syncthreads();

  // out2
  {
    float q[4][4] = {};
    for (int kk = 0; kk < HH; ++kk){
      float hv[4];
      #pragma unroll
      for (int rr = 0; rr < 4; ++rr) hv[rr] = p1L[(ng << 2) + rr][kk];
      float4 wv = *(const float4*)(o2w + kk*HH + (cg << 2));
      #pragma unroll
      for (int rr = 0; rr < 4; ++rr){
        q[rr][0] = fmaf(hv[rr], wv.x, q[rr][0]); q[rr][1] = fmaf(hv[rr], wv.y, q[rr][1]);
        q[rr][2] = fmaf(hv[rr], wv.z, q[rr][2]); q[rr][3] = fmaf(hv[rr], wv.w, q[rr][3]);
      }
    }
    float4 bb = *(const float4*)(o2b + (cg << 2));
    #pragma unroll
    for (int rr = 0; rr < 4; ++rr){
      p2L[(ng << 2) + rr][(cg << 2) + 0] = fmaxf(q[rr][0] + bb.x, 0.f);
      p2L[(ng << 2) + rr][(cg << 2) + 1] = fmaxf(q[rr][1] + bb.y, 0.f);
      p2L[(ng << 2) + rr][(cg << 2) + 2] = fmaxf(q[rr][2] + bb.z, 0.f);
      p2L[(ng << 2) + rr][(cg << 2) + 3] = fmaxf(q[rr][3] + bb.w, 0.f);
    }
  }
  __syncthreads();

  // out3: H -> 4, then pred = x + relu(...)
  if (tid < 128){
    int r = tid >> 2, c = tid & 3;
    int node = n0 + r;
    if (node < NN){
      float s = o3b[c];
      for (int kk = 0; kk < HH; ++kk) s = fmaf(p2L[r][kk], o3w[kk*CC + c], s);
      float v = fmaxf(s, 0.f);
      out[((size_t)t*NN + node)*CC + c] = xLs[r][c] + v;
    }
  }
}

extern "C" void kernel_launch(void* const* d_in, const int* in_sizes, int n_in,
                              void* d_out, int out_size, void* d_ws, size_t ws_size,
                              hipStream_t stream){
  const float* inputs = (const float*)d_in[0];
  const float* fc1w = (const float*)d_in[1];
  const float* fc1b = (const float*)d_in[2];
  const float* fc2w = (const float*)d_in[3];
  const float* fc2b = (const float*)d_in[4];
  const float* whr  = (const float*)d_in[5];
  const float* whi  = (const float*)d_in[6];
  const float* whh  = (const float*)d_in[7];
  const float* irw  = (const float*)d_in[8];
  const float* irb  = (const float*)d_in[9];
  const float* iiw  = (const float*)d_in[10];
  const float* iib  = (const float*)d_in[11];
  const float* inw  = (const float*)d_in[12];
  const float* inb  = (const float*)d_in[13];
  const float* o1w  = (const float*)d_in[14];
  const float* o1b  = (const float*)d_in[15];
  const float* o2w  = (const float*)d_in[16];
  const float* o2b  = (const float*)d_in[17];
  const float* o3w  = (const float*)d_in[18];
  const float* o3b  = (const float*)d_in[19];
  const int* edge   = (const int*)d_in[20];
  const int* burn   = (const int*)d_in[21];
  float* out = (float*)d_out;

  u8* ws = (u8*)d_ws;
  float* hid = (float*)(ws);               // N*H fp32 = 5,120,000 B
  float* agg = (float*)(ws + 5120000);     // N*H fp32 = 5,120,000 B
  float* UV  = (float*)(ws + 10240000);    // 6*N*H fp32 = 30,720,000 B

  hipMemsetAsync(hid, 0, 5120000, stream);

  const int nblk = (NN + 31) / 32;  // 313
  for (int t = 0; t < TT; ++t){
    hipMemsetAsync(agg, 0, 5120000, stream);
    hipLaunchKernelGGL(uv_kernel, dim3(nblk, 6), dim3(256), 0, stream, hid, fc1w, UV);
    hipLaunchKernelGGL(edge_kernel, dim3(EE/32), dim3(256), 0, stream,
                       edge, UV, fc1b, fc2b, fc2w, agg);
    hipLaunchKernelGGL(node_kernel, dim3(nblk), dim3(256), 0, stream,
                       inputs + (size_t)t*NN*CC, out + (size_t)(t > 0 ? t-1 : 0)*NN*CC, burn, t,
                       agg, hid, whr, whi, whh, irw, irb, iiw, iib, inw, inb,
                       o1w, o1b, o2w, o2b, o3w, o3b, out);
  }
}